// Round 20
// baseline (308.329 us; speedup 1.0000x reference)
//
#include <hip/hip_runtime.h>
#include <hip/hip_bf16.h>

// BaseTimeAttention: out = ((softmax(rope(xWq)·rope(xWk)^T/sqrt(d)))·(xWv)) @ Wo^T
// bf16 MFMA everywhere (no fp32 MFMA on CDNA4), fp32 accum + fp32 softmax (exp2 domain).
// d_ws layout (bf16 elems): xb/aob(8.4M) | qb(8.4M) | kb(8.4M) | vtb(8.4M) | wsl(4.2M) = 72MB
// d_out doubles as scratch for Wq/Wk/Wv bf16 (25.2MB < 33.5MB; dead before the final GEMM
// overwrites d_out); Wo bf16 lives in wsl. RoPE (+SC2 for Q) is fused into gemm_qkv's
// EPILOGUE via a cross-wave LDS exchange (pair d/d+64 lives in partner wave wid^1) —
// no separate rope kernel, rope applied to f32 accumulators.

typedef __attribute__((ext_vector_type(8))) short short8;
typedef __attribute__((ext_vector_type(4))) float f32x4;
typedef __attribute__((ext_vector_type(4))) unsigned short us4;
typedef __attribute__((ext_vector_type(4))) unsigned int u32x4;

__device__ __forceinline__ void gll16(const void* g, void* l) {
  __builtin_amdgcn_global_load_lds((const __attribute__((address_space(1))) void*)g,
                                   (__attribute__((address_space(3))) void*)l, 16, 0, 0);
}

__device__ __forceinline__ unsigned short f2bf(float f) {
  __hip_bfloat16 h = __float2bfloat16(f);
  return *reinterpret_cast<unsigned short*>(&h);
}

__device__ __forceinline__ float bf2f(short s) {
  union { unsigned int u; float f; } c;
  c.u = ((unsigned int)(unsigned short)s) << 16;
  return c.f;
}

// pack two f32 -> one u32 of 2 bf16 (lo,hi) via HW instruction
__device__ __forceinline__ unsigned int cvtpk(float lo, float hi) {
  unsigned int r;
  asm("v_cvt_pk_bf16_f32 %0, %1, %2" : "=v"(r) : "v"(lo), "v"(hi));
  return r;
}

// T1 XCD-aware block remap (bijective; requires gridDim.y % 8 == 0).
__device__ __forceinline__ void xcd_remap(int& Bx, int& By) {
  const int flat = blockIdx.y * gridDim.x + blockIdx.x;
  const int xcd = flat & 7, idx = flat >> 3;
  const int ppx = gridDim.y >> 3;  // W-panels per XCD
  By = xcd * ppx + (idx % ppx);
  Bx = idx / ppx;
}

// one launch: cast x + Wq + Wk + Wv + Wo (f32 -> bf16, float4-wide)
__global__ __launch_bounds__(256) void cast5(const float* __restrict__ x,
                                             const float* __restrict__ wq,
                                             const float* __restrict__ wk,
                                             const float* __restrict__ wv,
                                             const float* __restrict__ wo,
                                             __hip_bfloat16* __restrict__ xb,
                                             __hip_bfloat16* __restrict__ dq,
                                             __hip_bfloat16* __restrict__ dk,
                                             __hip_bfloat16* __restrict__ dv,
                                             __hip_bfloat16* __restrict__ dwo,
                                             int nx4, int nw4) {
  int i = blockIdx.x * 256 + threadIdx.x;
  const float* in;
  __hip_bfloat16* out;
  int j = i;
  if (i < nx4) { in = x; out = xb; }
  else if ((j = i - nx4) < nw4) { in = wq; out = dq; }
  else if ((j -= nw4) < nw4) { in = wk; out = dk; }
  else if ((j -= nw4) < nw4) { in = wv; out = dv; }
  else if ((j -= nw4) < nw4) { in = wo; out = dwo; }
  else return;
  const float4 v = reinterpret_cast<const float4*>(in)[j];
  us4 o;
  o[0] = f2bf(v.x); o[1] = f2bf(v.y); o[2] = f2bf(v.z); o[3] = f2bf(v.w);
  *reinterpret_cast<us4*>(out + (size_t)j * 4) = o;
}

// ---- shared GEMM core v2 (proven R12/R14/R16/R18): counted-vmcnt double-buffered ring (T4).
// C = A(MxK) * Bt(NxK)^T, 128x128 tile, BK=64, 4 waves (2x2 of 64x64).
// LDS tiles [128 rows][64 cols bf16], XOR-swizzled: phys 16B-chunk = logical ^ (row&7).
template <typename EPI>
__device__ __forceinline__ void gemm_core(const __hip_bfloat16* A, const __hip_bfloat16* Bt,
                                          int row0, int col0, int K, EPI epi) {
  __shared__ char As[2][16384];
  __shared__ char Bs[2][16384];
  const int tid = threadIdx.x;
  const int lane = tid & 63, wid = tid >> 6;
  const int l15 = lane & 15, l4 = lane >> 4;
  const int wm = (wid >> 1) * 64, wn = (wid & 1) * 64;

  f32x4 acc[4][4] = {};

  const int rs = lane >> 3;       // row within 1KB staging chunk (8 rows x 128B)
  const int cs = lane & 7;        // 16B chunk within row
  const int cg = cs ^ rs;         // pre-swizzled global source chunk
  const char* Ab = (const char*)A;
  const char* Bb = (const char*)Bt;
  const size_t Kb = (size_t)K * 2;
  const int NT = K >> 6;          // K-tiles of 64

#define GSTAGE(T, S)                                                                      \
  {                                                                                       \
    const int k0_ = (T) << 6;                                                             \
    _Pragma("unroll") for (int c_ = 0; c_ < 4; ++c_) {                                    \
      const int cid_ = wid * 4 + c_;                                                      \
      const int r_ = cid_ * 8 + rs;                                                       \
      gll16(Ab + (size_t)(row0 + r_) * Kb + (size_t)k0_ * 2 + cg * 16, As[S] + cid_ * 1024); \
      gll16(Bb + (size_t)(col0 + r_) * Kb + (size_t)k0_ * 2 + cg * 16, Bs[S] + cid_ * 1024); \
    }                                                                                     \
  }

  GSTAGE(0, 0);
  GSTAGE(1, 1);
  asm volatile("s_waitcnt vmcnt(8)" ::: "memory");  // tile 0's 8 loads landed
  __builtin_amdgcn_s_barrier();

  for (int t = 0; t < NT; ++t) {
    const int s = t & 1;
    short8 a[2][4], b[2][4];
#pragma unroll
    for (int kc = 0; kc < 2; ++kc)
#pragma unroll
      for (int i = 0; i < 4; ++i) {
        const int ra = wm + i * 16 + l15;
        a[kc][i] = *(const short8*)(As[s] + ra * 128 + (((kc * 4 + l4) ^ (ra & 7)) * 16));
        const int rb = wn + i * 16 + l15;
        b[kc][i] = *(const short8*)(Bs[s] + rb * 128 + (((kc * 4 + l4) ^ (rb & 7)) * 16));
      }
    asm volatile("s_waitcnt lgkmcnt(0)" ::: "memory");  // my reads of slot s retired
    __builtin_amdgcn_sched_barrier(0);
    __builtin_amdgcn_s_barrier();                       // bar1: ALL waves' reads retired
    if (t + 2 < NT) {
      GSTAGE(t + 2, s);                                 // overwrite freed slot
      asm volatile("s_waitcnt vmcnt(8)" ::: "memory");  // tile t+1 (8 oldest) landed
    } else if (t + 2 == NT) {
      asm volatile("s_waitcnt vmcnt(0)" ::: "memory");  // epilogue drain: tile NT-1
    }
    __builtin_amdgcn_s_barrier();                       // bar2: slot s^1 published
#pragma unroll
    for (int kc = 0; kc < 2; ++kc) {
      __builtin_amdgcn_s_setprio(1);
#pragma unroll
      for (int i = 0; i < 4; ++i)
#pragma unroll
        for (int j = 0; j < 4; ++j)
          acc[i][j] = __builtin_amdgcn_mfma_f32_16x16x32_bf16(a[kc][i], b[kc][j], acc[i][j], 0, 0, 0);
      __builtin_amdgcn_s_setprio(0);
    }
  }
  epi(acc, wm, wn, l15, l4);
#undef GSTAGE
}

// MODE 0: bf16 row-major. MODE 1: f32 row-major.
// MODE 2: V^T per (b,h), kv-PERMUTED: phys = (kv&~31)+((kv>>2)&3)*8+((kv>>4)&1)*4+(kv&3).
template <int MODE>
__global__ __launch_bounds__(256) void gemm_bt(const __hip_bfloat16* __restrict__ A,
                                               const __hip_bfloat16* __restrict__ Bt,
                                               void* __restrict__ Cout,
                                               int M, int N, int K) {
  int Bx, By;
  xcd_remap(Bx, By);  // T1: same-XCD blocks share W-panels + consecutive same A-tile
  const int row0 = Bx * 128, col0 = By * 128;
  gemm_core(A, Bt, row0, col0, K, [=](f32x4 (&acc)[4][4], int wm, int wn, int l15, int l4) {
    if (MODE == 2) {
      __hip_bfloat16* vt = (__hip_bfloat16*)Cout;
#pragma unroll
      for (int i = 0; i < 4; ++i) {
        const int gm = row0 + wm + i * 16 + l4 * 4;
        const int bb = gm >> 11, kvb = gm & 2047;
        const int phys = (kvb & ~31) + (((kvb >> 2) & 3) << 3) + (((kvb >> 4) & 1) << 2);
#pragma unroll
        for (int j = 0; j < 4; ++j) {
          const int gn = col0 + wn + j * 16 + l15;
          const int h = gn >> 7, d = gn & 127;
          us4 o;
          o[0] = f2bf(acc[i][j][0]); o[1] = f2bf(acc[i][j][1]);
          o[2] = f2bf(acc[i][j][2]); o[3] = f2bf(acc[i][j][3]);
          *reinterpret_cast<us4*>(vt + ((size_t)((bb * 16 + h) * 128 + d) * 2048 + phys)) = o;
        }
      }
    } else {
#pragma unroll
      for (int i = 0; i < 4; ++i)
#pragma unroll
        for (int j = 0; j < 4; ++j) {
          const int gn = col0 + wn + j * 16 + l15;
#pragma unroll
          for (int r = 0; r < 4; ++r) {
            const int gm = row0 + wm + i * 16 + l4 * 4 + r;
            if (MODE == 0)
              ((__hip_bfloat16*)Cout)[(size_t)gm * N + gn] = __float2bfloat16(acc[i][j][r]);
            else
              ((float*)Cout)[(size_t)gm * N + gn] = acc[i][j][r];
          }
        }
    }
  });
}

// fused QKV GEMM with FUSED ROPE on Q/K: grid (32, 48). By 0-15 -> Wq->qb; 16-31 ->
// Wk->kb; 32-47 -> Wv->vtb (kv-permuted V^T). A = xb for all. T1 XCD remap.
// Rope epilogue (sel 0/1): pair (d, d+64) lives in partner wave wid^1 (wn^64) at the
// SAME lane/(i,j,r). Exchange one i-group at a time through a 16KB LDS buffer
// (wave region 4KB, addr j*1024 + lane*16 -> conflict-free b128), 2 barriers per group.
// Rope applied to f32 acc (better rounding); Q also scaled by SC2=(1/sqrt(128))*log2e.
__global__ __launch_bounds__(256) void gemm_qkv(const __hip_bfloat16* __restrict__ A,
                                                const __hip_bfloat16* __restrict__ Wq,
                                                const __hip_bfloat16* __restrict__ Wk,
                                                const __hip_bfloat16* __restrict__ Wv,
                                                __hip_bfloat16* __restrict__ qb,
                                                __hip_bfloat16* __restrict__ kb,
                                                __hip_bfloat16* __restrict__ vtb) {
  __shared__ char xch[16384];  // rope cross-wave exchange buffer (epilogue only)
  int Bx, By;
  xcd_remap(Bx, By);
  const int row0 = Bx * 128;
  const int sel = By >> 4;                 // 0=q, 1=k, 2=v
  const int col0 = (By & 15) * 128;
  const __hip_bfloat16* Bt = (sel == 0) ? Wq : (sel == 1) ? Wk : Wv;
  __hip_bfloat16* outq = (sel == 0) ? qb : kb;
  char* xchp = xch;

  gemm_core(A, Bt, row0, col0, 2048, [=](f32x4 (&acc)[4][4], int wm, int wn, int l15, int l4) {
    if (sel == 2) {
#pragma unroll
      for (int i = 0; i < 4; ++i) {
        const int gm = row0 + wm + i * 16 + l4 * 4;
        const int bb = gm >> 11, kvb = gm & 2047;
        const int phys = (kvb & ~31) + (((kvb >> 2) & 3) << 3) + (((kvb >> 4) & 1) << 2);
#pragma unroll
        for (int j = 0; j < 4; ++j) {
          const int gn = col0 + wn + j * 16 + l15;
          const int h = gn >> 7, d = gn & 127;
          us4 o;
          o[0] = f2bf(acc[i][j][0]); o[1] = f2bf(acc[i][j][1]);
          o[2] = f2bf(acc[i][j][2]); o[3] = f2bf(acc[i][j][3]);
          *reinterpret_cast<us4*>(vtb + ((size_t)((bb * 16 + h) * 128 + d) * 2048 + phys)) = o;
        }
      }
    } else {
      // rope epilogue for Q (sel 0, +SC2) and K (sel 1)
      const int wid = threadIdx.x >> 6, lane = threadIdx.x & 63;
      const float qs = (sel == 0) ? 0.1275224187f : 1.0f;
      const int lo_half = (wn == 0);  // this wave holds x1 (d<64); partner holds x2
#pragma unroll
      for (int i = 0; i < 4; ++i) {
#pragma unroll
        for (int j = 0; j < 4; ++j)
          *(f32x4*)(xchp + wid * 4096 + j * 1024 + lane * 16) = acc[i][j];
        __syncthreads();
        f32x4 pacc[4];
#pragma unroll
        for (int j = 0; j < 4; ++j)
          pacc[j] = *(const f32x4*)(xchp + (wid ^ 1) * 4096 + j * 1024 + lane * 16);
#pragma unroll
        for (int j = 0; j < 4; ++j) {
          const int ii = j * 16 + l15;  // frequency index = d & 63 (same for both halves)
          const float invf = exp2f((float)ii * -0.20762050593046f);  // 10000^(-ii/64)
          const int gn = col0 + wn + j * 16 + l15;
#pragma unroll
          for (int r = 0; r < 4; ++r) {
            const int gm = row0 + wm + i * 16 + l4 * 4 + r;
            const int pos = gm & 2047;
            float sv, cv;
            sincosf((float)pos * invf, &sv, &cv);
            const float mine = acc[i][j][r], other = pacc[j][r];
            // lo half: out = x1*cos - x2*sin (x1=mine); hi half: out = x1*sin + x2*cos (x2=mine)
            const float ov = lo_half ? (mine * cv - other * sv) * qs
                                     : (other * sv + mine * cv) * qs;
            union { unsigned short u; __hip_bfloat16 h; } cvt;
            cvt.u = f2bf(ov);
            outq[(size_t)gm * 2048 + gn] = cvt.h;
          }
        }
        __syncthreads();  // before next i-group overwrites xch
      }
    }
  });
}

// Flash attention v10 (R16/R18-proven): K+VT LDS counted-vmcnt ring, 64KB, gll16 with
// pre-swizzled source, 8 loads/wave/tile -> vmcnt(8), never 0 in steady state.
// Q pre-roped+pre-scaled (by gemm_qkv epilogue) -> P = exp2f(sacc); lr via ones-row MFMA.
// grid 512 (qt=bx>>5, bh=bx&31; bx%8=bh%8 pins each (b,h)'s 1MB KV set to one XCD L2).
// 4 waves x 32 q-rows (QBLK=128). Fixed-max softmax (scores bounded, fp32-safe).
// kv-permuted V^T (V-frag = one b128 ds_read); swapped QK^T / PV (S^T, O^T in-register).
__global__ __launch_bounds__(256) void flash_k(const __hip_bfloat16* __restrict__ q,
                                               const __hip_bfloat16* __restrict__ k,
                                               const __hip_bfloat16* __restrict__ vt,
                                               __hip_bfloat16* __restrict__ ao) {
  __shared__ char Ks[2][16384];   // K tile [64 kv][128 d], swizzled
  __shared__ char VTs[2][16384];  // V^T tile [128 d][64 kv permuted], swizzled
  const int tid = threadIdx.x, lane = tid & 63, wid = tid >> 6;
  const int bx = blockIdx.x;
  const int qt = bx >> 5, bh = bx & 31, b = bh >> 4, h = bh & 15;
  const int l15 = lane & 15, l4 = lane >> 4;

  short8 qf[2][4];
  const char* qB = (const char*)q;
#pragma unroll
  for (int mi = 0; mi < 2; ++mi)
#pragma unroll
    for (int kc = 0; kc < 4; ++kc) {
      const size_t off =
          ((size_t)(b * 2048 + qt * 128 + wid * 32 + mi * 16 + l15) * 2048 + h * 128 + kc * 32 + l4 * 8) * 2;
      qf[mi][kc] = *(const short8*)(qB + off);
    }

  f32x4 oacc[2][8] = {};
  f32x4 lracc[2] = {};  // ones-row MFMA accumulates sum(P) per q-col; rows identical

  const short8 ones = {(short)0x3F80, (short)0x3F80, (short)0x3F80, (short)0x3F80,
                       (short)0x3F80, (short)0x3F80, (short)0x3F80, (short)0x3F80};  // bf16 1.0

  const char* kbase = (const char*)k + ((size_t)(b * 2048) * 2048 + h * 128) * 2;
  const char* vtbase = (const char*)vt + ((size_t)bh * 128 * 2048) * 2;

  // gll16 staging geometry. K tile: 16 chunks of 1KB = 4 kv-rows x 256B;
  // krow=lane>>4, kcol=lane&15. VT tile: 16 chunks = 8 d-rows x 128B; vrow=lane>>3,
  // vcol=lane&7. LDS dest linear (lane*16), global source pre-swizzled ^(row&7).
  const int krow = lane >> 4, kcol = lane & 15;
  const int vrow = lane >> 3, vcol = lane & 7;

#define GSTAGE(T, S)                                                                          \
  {                                                                                           \
    const int kv0_ = (T)*64;                                                                  \
    _Pragma("unroll") for (int c_ = 0; c_ < 4; ++c_) {                                        \
      const int cid_ = wid * 4 + c_;                                                          \
      const int rk_ = cid_ * 4 + krow;                                                        \
      gll16(kbase + (size_t)(kv0_ + rk_) * 4096 + ((kcol ^ (rk_ & 7)) * 16),                  \
            Ks[S] + cid_ * 1024);                                                             \
      const int rv_ = cid_ * 8 + vrow;                                                        \
      gll16(vtbase + (size_t)rv_ * 4096 + (size_t)kv0_ * 2 + ((vcol ^ (rv_ & 7)) * 16),       \
            VTs[S] + cid_ * 1024);                                                            \
    }                                                                                         \
  }

  GSTAGE(0, 0);
  GSTAGE(1, 1);
  asm volatile("s_waitcnt vmcnt(8)" ::: "memory");  // tile 0's 8 loads landed
  __builtin_amdgcn_s_barrier();

  for (int t = 0; t < 32; ++t) {
    const int s = t & 1;

    // S^T = (Q K^T)^T : mfma(A=K rows, B=Q rows) -> C[kv][q], col=l15=q, row=l4*4+r=kv
    f32x4 sacc[2][4] = {};
#pragma unroll
    for (int kc = 0; kc < 4; ++kc) {
      short8 kf[4];
#pragma unroll
      for (int ni = 0; ni < 4; ++ni) {
        const int r = ni * 16 + l15;
        kf[ni] = *(const short8*)(Ks[s] + r * 256 + (((kc * 4 + l4) ^ (r & 7)) * 16));
      }
#pragma unroll
      for (int mi = 0; mi < 2; ++mi)
#pragma unroll
        for (int ni = 0; ni < 4; ++ni)
          sacc[mi][ni] = __builtin_amdgcn_mfma_f32_16x16x32_bf16(kf[ni], qf[mi][kc], sacc[mi][ni], 0, 0, 0);
    }

    // fixed-max softmax: Q carries SC2 -> P = exp2f(sacc) directly (|sacc| <= ~8.5,
    // P in [2^-10, ~360], fp32-safe). No row max, no mul, no row-sum VALU.
    unsigned int W[2][4][2];
#pragma unroll
    for (int mi = 0; mi < 2; ++mi)
#pragma unroll
      for (int ni = 0; ni < 4; ++ni) {
        W[mi][ni][0] = cvtpk(exp2f(sacc[mi][ni][0]), exp2f(sacc[mi][ni][1]));
        W[mi][ni][1] = cvtpk(exp2f(sacc[mi][ni][2]), exp2f(sacc[mi][ni][3]));
      }

    // O^T += (V^T) P ; lr += (ones) P  (matrix pipe computes the denominator)
#pragma unroll
    for (int kc = 0; kc < 2; ++kc) {
      union { u32x4 u; short8 s; } pfu[2];
#pragma unroll
      for (int mi = 0; mi < 2; ++mi) {
        pfu[mi].u[0] = W[mi][kc * 2][0];
        pfu[mi].u[1] = W[mi][kc * 2][1];
        pfu[mi].u[2] = W[mi][kc * 2 + 1][0];
        pfu[mi].u[3] = W[mi][kc * 2 + 1][1];
      }
#pragma unroll
      for (int nd = 0; nd < 8; ++nd) {
        const int r = nd * 16 + l15;
        const short8 vf = *(const short8*)(
            VTs[s] + r * 128 + (((kc * 4 + l4) ^ (r & 7)) * 16));
#pragma unroll
        for (int mi = 0; mi < 2; ++mi)
          oacc[mi][nd] = __builtin_amdgcn_mfma_f32_16x16x32_bf16(vf, pfu[mi].s, oacc[mi][nd], 0, 0, 0);
      }
#pragma unroll
      for (int mi = 0; mi < 2; ++mi)
        lracc[mi] = __builtin_amdgcn_mfma_f32_16x16x32_bf16(ones, pfu[mi].s, lracc[mi], 0, 0, 0);
    }

    asm volatile("s_waitcnt lgkmcnt(0)" ::: "memory");  // my reads of slot s retired
    __builtin_amdgcn_sched_barrier(0);
    __builtin_amdgcn_s_barrier();                       // bar1: ALL waves' reads retired
    if (t + 2 < 32) {
      GSTAGE(t + 2, s);                                 // overwrite freed slot
      asm volatile("s_waitcnt vmcnt(8)" ::: "memory");  // tile t+1 (8 oldest) landed
    } else if (t + 2 == 32) {
      asm volatile("s_waitcnt vmcnt(0)" ::: "memory");  // epilogue drain: tile 31
    }
    __builtin_amdgcn_s_barrier();                       // bar2: slot s^1 published
  }

  // epilogue: O^T layout -> lane holds q = mi*16+l15, d = nd*16 + l4*4 + r (4 consecutive)
#pragma unroll
  for (int mi = 0; mi < 2; ++mi) {
    const float inv = 1.f / lracc[mi][0];
    const int qrow = qt * 128 + wid * 32 + mi * 16 + l15;
    const size_t rowoff = ((size_t)(b * 2048 + qrow)) * 2048 + h * 128;
#pragma unroll
    for (int nd = 0; nd < 8; ++nd) {
      us4 o;
      o[0] = f2bf(oacc[mi][nd][0] * inv);
      o[1] = f2bf(oacc[mi][nd][1] * inv);
      o[2] = f2bf(oacc[mi][nd][2] * inv);
      o[3] = f2bf(oacc[mi][nd][3] * inv);
      *reinterpret_cast<us4*>(ao + rowoff + nd * 16 + l4 * 4) = o;
    }
  }
#undef GSTAGE
}

extern "C" void kernel_launch(void* const* d_in, const int* in_sizes, int n_in,
                              void* d_out, int out_size, void* d_ws, size_t ws_size,
                              hipStream_t stream) {
  const float* x  = (const float*)d_in[0];
  const float* Wq = (const float*)d_in[1];
  const float* Wk = (const float*)d_in[2];
  const float* Wv = (const float*)d_in[3];
  const float* Wo = (const float*)d_in[4];
  float* out = (float*)d_out;

  const size_t MK = (size_t)4096 * 2048;  // 8,388,608
  const size_t WN = (size_t)2048 * 2048;  // 4,194,304
  if (ws_size < (4 * MK + WN) * 2) return;  // need ~72MB

  __hip_bfloat16* ws  = (__hip_bfloat16*)d_ws;
  __hip_bfloat16* xb  = ws;             // also reused as attention output (aob)
  __hip_bfloat16* qb  = ws + MK;
  __hip_bfloat16* kb  = ws + 2 * MK;
  __hip_bfloat16* vtb = ws + 3 * MK;
  __hip_bfloat16* wsl = ws + 4 * MK;    // holds Wo bf16 for the final GEMM
  __hip_bfloat16* aob = xb;
  // d_out as scratch for Wq/Wk/Wv bf16 (dead before final GEMM overwrites d_out)
  __hip_bfloat16* dq = (__hip_bfloat16*)d_out;
  __hip_bfloat16* dk = dq + WN;
  __hip_bfloat16* dv = dk + WN;

  const int nx4 = (int)(MK / 4), nw4 = (int)(WN / 4);
  cast5<<<dim3((nx4 + 4 * nw4) / 256), 256, 0, stream>>>(x, Wq, Wk, Wv, Wo,
                                                         xb, dq, dk, dv, wsl, nx4, nw4);
  gemm_qkv<<<dim3(32, 48), 256, 0, stream>>>(xb, dq, dk, dv, qb, kb, vtb);
  flash_k<<<512, 256, 0, stream>>>(qb, kb, vtb, aob);
  gemm_bt<1><<<dim3(32, 16), 256, 0, stream>>>(aob, wsl, out, 4096, 2048, 2048);
}

// Round 21
// 254.519 us; speedup vs baseline: 1.2114x; 1.2114x over previous
//
#include <hip/hip_runtime.h>
#include <hip/hip_bf16.h>

// BaseTimeAttention: out = ((softmax(rope(xWq)·rope(xWk)^T/sqrt(d)))·(xWv)) @ Wo^T
// bf16 MFMA everywhere (no fp32 MFMA on CDNA4), fp32 accum + fp32 softmax (exp2 domain).
// d_ws layout (bf16 elems): xb/aob(8.4M) | qb(8.4M) | kb(8.4M) | vtb(8.4M) | wsl(4.2M) = 72MB
// d_out doubles as scratch for Wq/Wk/Wv bf16 (25.2MB < 33.5MB; dead before the final GEMM
// overwrites d_out); Wo bf16 lives in wsl from the start (nothing else touches wsl).
// R21 = exact revert to R18 (best measured 254.8us) after R20's rope-fusion write-amp
// regression (scalar epilogue stores -> 5x WRITE_SIZE).

typedef __attribute__((ext_vector_type(8))) short short8;
typedef __attribute__((ext_vector_type(4))) float f32x4;
typedef __attribute__((ext_vector_type(4))) unsigned short us4;
typedef __attribute__((ext_vector_type(4))) unsigned int u32x4;

__device__ __forceinline__ void gll16(const void* g, void* l) {
  __builtin_amdgcn_global_load_lds((const __attribute__((address_space(1))) void*)g,
                                   (__attribute__((address_space(3))) void*)l, 16, 0, 0);
}

__device__ __forceinline__ unsigned short f2bf(float f) {
  __hip_bfloat16 h = __float2bfloat16(f);
  return *reinterpret_cast<unsigned short*>(&h);
}

__device__ __forceinline__ float bf2f(short s) {
  union { unsigned int u; float f; } c;
  c.u = ((unsigned int)(unsigned short)s) << 16;
  return c.f;
}

// pack two f32 -> one u32 of 2 bf16 (lo,hi) via HW instruction
__device__ __forceinline__ unsigned int cvtpk(float lo, float hi) {
  unsigned int r;
  asm("v_cvt_pk_bf16_f32 %0, %1, %2" : "=v"(r) : "v"(lo), "v"(hi));
  return r;
}

// T1 XCD-aware block remap (bijective; requires gridDim.y % 8 == 0).
__device__ __forceinline__ void xcd_remap(int& Bx, int& By) {
  const int flat = blockIdx.y * gridDim.x + blockIdx.x;
  const int xcd = flat & 7, idx = flat >> 3;
  const int ppx = gridDim.y >> 3;  // W-panels per XCD
  By = xcd * ppx + (idx % ppx);
  Bx = idx / ppx;
}

// one launch: cast x + Wq + Wk + Wv + Wo (f32 -> bf16, float4-wide)
__global__ __launch_bounds__(256) void cast5(const float* __restrict__ x,
                                             const float* __restrict__ wq,
                                             const float* __restrict__ wk,
                                             const float* __restrict__ wv,
                                             const float* __restrict__ wo,
                                             __hip_bfloat16* __restrict__ xb,
                                             __hip_bfloat16* __restrict__ dq,
                                             __hip_bfloat16* __restrict__ dk,
                                             __hip_bfloat16* __restrict__ dv,
                                             __hip_bfloat16* __restrict__ dwo,
                                             int nx4, int nw4) {
  int i = blockIdx.x * 256 + threadIdx.x;
  const float* in;
  __hip_bfloat16* out;
  int j = i;
  if (i < nx4) { in = x; out = xb; }
  else if ((j = i - nx4) < nw4) { in = wq; out = dq; }
  else if ((j -= nw4) < nw4) { in = wk; out = dk; }
  else if ((j -= nw4) < nw4) { in = wv; out = dv; }
  else if ((j -= nw4) < nw4) { in = wo; out = dwo; }
  else return;
  const float4 v = reinterpret_cast<const float4*>(in)[j];
  us4 o;
  o[0] = f2bf(v.x); o[1] = f2bf(v.y); o[2] = f2bf(v.z); o[3] = f2bf(v.w);
  *reinterpret_cast<us4*>(out + (size_t)j * 4) = o;
}

// ---- shared GEMM core v2 (proven R12/R14/R16/R18): counted-vmcnt double-buffered ring (T4).
// C = A(MxK) * Bt(NxK)^T, 128x128 tile, BK=64, 4 waves (2x2 of 64x64).
// LDS tiles [128 rows][64 cols bf16], XOR-swizzled: phys 16B-chunk = logical ^ (row&7).
template <typename EPI>
__device__ __forceinline__ void gemm_core(const __hip_bfloat16* A, const __hip_bfloat16* Bt,
                                          int row0, int col0, int K, EPI epi) {
  __shared__ char As[2][16384];
  __shared__ char Bs[2][16384];
  const int tid = threadIdx.x;
  const int lane = tid & 63, wid = tid >> 6;
  const int l15 = lane & 15, l4 = lane >> 4;
  const int wm = (wid >> 1) * 64, wn = (wid & 1) * 64;

  f32x4 acc[4][4] = {};

  const int rs = lane >> 3;       // row within 1KB staging chunk (8 rows x 128B)
  const int cs = lane & 7;        // 16B chunk within row
  const int cg = cs ^ rs;         // pre-swizzled global source chunk
  const char* Ab = (const char*)A;
  const char* Bb = (const char*)Bt;
  const size_t Kb = (size_t)K * 2;
  const int NT = K >> 6;          // K-tiles of 64

#define GSTAGE(T, S)                                                                      \
  {                                                                                       \
    const int k0_ = (T) << 6;                                                             \
    _Pragma("unroll") for (int c_ = 0; c_ < 4; ++c_) {                                    \
      const int cid_ = wid * 4 + c_;                                                      \
      const int r_ = cid_ * 8 + rs;                                                       \
      gll16(Ab + (size_t)(row0 + r_) * Kb + (size_t)k0_ * 2 + cg * 16, As[S] + cid_ * 1024); \
      gll16(Bb + (size_t)(col0 + r_) * Kb + (size_t)k0_ * 2 + cg * 16, Bs[S] + cid_ * 1024); \
    }                                                                                     \
  }

  GSTAGE(0, 0);
  GSTAGE(1, 1);
  asm volatile("s_waitcnt vmcnt(8)" ::: "memory");  // tile 0's 8 loads landed
  __builtin_amdgcn_s_barrier();

  for (int t = 0; t < NT; ++t) {
    const int s = t & 1;
    short8 a[2][4], b[2][4];
#pragma unroll
    for (int kc = 0; kc < 2; ++kc)
#pragma unroll
      for (int i = 0; i < 4; ++i) {
        const int ra = wm + i * 16 + l15;
        a[kc][i] = *(const short8*)(As[s] + ra * 128 + (((kc * 4 + l4) ^ (ra & 7)) * 16));
        const int rb = wn + i * 16 + l15;
        b[kc][i] = *(const short8*)(Bs[s] + rb * 128 + (((kc * 4 + l4) ^ (rb & 7)) * 16));
      }
    asm volatile("s_waitcnt lgkmcnt(0)" ::: "memory");  // my reads of slot s retired
    __builtin_amdgcn_sched_barrier(0);
    __builtin_amdgcn_s_barrier();                       // bar1: ALL waves' reads retired
    if (t + 2 < NT) {
      GSTAGE(t + 2, s);                                 // overwrite freed slot
      asm volatile("s_waitcnt vmcnt(8)" ::: "memory");  // tile t+1 (8 oldest) landed
    } else if (t + 2 == NT) {
      asm volatile("s_waitcnt vmcnt(0)" ::: "memory");  // epilogue drain: tile NT-1
    }
    __builtin_amdgcn_s_barrier();                       // bar2: slot s^1 published
#pragma unroll
    for (int kc = 0; kc < 2; ++kc) {
      __builtin_amdgcn_s_setprio(1);
#pragma unroll
      for (int i = 0; i < 4; ++i)
#pragma unroll
        for (int j = 0; j < 4; ++j)
          acc[i][j] = __builtin_amdgcn_mfma_f32_16x16x32_bf16(a[kc][i], b[kc][j], acc[i][j], 0, 0, 0);
      __builtin_amdgcn_s_setprio(0);
    }
  }
  epi(acc, wm, wn, l15, l4);
#undef GSTAGE
}

// MODE 0: bf16 row-major. MODE 1: f32 row-major.
// MODE 2: V^T per (b,h), kv-PERMUTED: phys = (kv&~31)+((kv>>2)&3)*8+((kv>>4)&1)*4+(kv&3).
template <int MODE>
__global__ __launch_bounds__(256) void gemm_bt(const __hip_bfloat16* __restrict__ A,
                                               const __hip_bfloat16* __restrict__ Bt,
                                               void* __restrict__ Cout,
                                               int M, int N, int K) {
  int Bx, By;
  xcd_remap(Bx, By);  // T1: same-XCD blocks share W-panels + consecutive same A-tile
  const int row0 = Bx * 128, col0 = By * 128;
  gemm_core(A, Bt, row0, col0, K, [=](f32x4 (&acc)[4][4], int wm, int wn, int l15, int l4) {
    if (MODE == 2) {
      __hip_bfloat16* vt = (__hip_bfloat16*)Cout;
#pragma unroll
      for (int i = 0; i < 4; ++i) {
        const int gm = row0 + wm + i * 16 + l4 * 4;
        const int bb = gm >> 11, kvb = gm & 2047;
        const int phys = (kvb & ~31) + (((kvb >> 2) & 3) << 3) + (((kvb >> 4) & 1) << 2);
#pragma unroll
        for (int j = 0; j < 4; ++j) {
          const int gn = col0 + wn + j * 16 + l15;
          const int h = gn >> 7, d = gn & 127;
          us4 o;
          o[0] = f2bf(acc[i][j][0]); o[1] = f2bf(acc[i][j][1]);
          o[2] = f2bf(acc[i][j][2]); o[3] = f2bf(acc[i][j][3]);
          *reinterpret_cast<us4*>(vt + ((size_t)((bb * 16 + h) * 128 + d) * 2048 + phys)) = o;
        }
      }
    } else {
#pragma unroll
      for (int i = 0; i < 4; ++i)
#pragma unroll
        for (int j = 0; j < 4; ++j) {
          const int gn = col0 + wn + j * 16 + l15;
#pragma unroll
          for (int r = 0; r < 4; ++r) {
            const int gm = row0 + wm + i * 16 + l4 * 4 + r;
            if (MODE == 0)
              ((__hip_bfloat16*)Cout)[(size_t)gm * N + gn] = __float2bfloat16(acc[i][j][r]);
            else
              ((float*)Cout)[(size_t)gm * N + gn] = acc[i][j][r];
          }
        }
    }
  });
}

// fused QKV GEMM: grid (32, 48). By 0-15 -> Wq->qb (row-major bf16); 16-31 -> Wk->kb;
// 32-47 -> Wv->vtb (kv-permuted V^T layout). A = xb for all. T1 XCD remap.
__global__ __launch_bounds__(256) void gemm_qkv(const __hip_bfloat16* __restrict__ A,
                                                const __hip_bfloat16* __restrict__ Wq,
                                                const __hip_bfloat16* __restrict__ Wk,
                                                const __hip_bfloat16* __restrict__ Wv,
                                                __hip_bfloat16* __restrict__ qb,
                                                __hip_bfloat16* __restrict__ kb,
                                                __hip_bfloat16* __restrict__ vtb) {
  int Bx, By;
  xcd_remap(Bx, By);
  const int row0 = Bx * 128;
  const int sel = By >> 4;                 // 0=q, 1=k, 2=v
  const int col0 = (By & 15) * 128;
  const __hip_bfloat16* Bt = (sel == 0) ? Wq : (sel == 1) ? Wk : Wv;
  __hip_bfloat16* outq = (sel == 0) ? qb : kb;

  gemm_core(A, Bt, row0, col0, 2048, [=](f32x4 (&acc)[4][4], int wm, int wn, int l15, int l4) {
    if (sel == 2) {
#pragma unroll
      for (int i = 0; i < 4; ++i) {
        const int gm = row0 + wm + i * 16 + l4 * 4;
        const int bb = gm >> 11, kvb = gm & 2047;
        const int phys = (kvb & ~31) + (((kvb >> 2) & 3) << 3) + (((kvb >> 4) & 1) << 2);
#pragma unroll
        for (int j = 0; j < 4; ++j) {
          const int gn = col0 + wn + j * 16 + l15;
          const int h = gn >> 7, d = gn & 127;
          us4 o;
          o[0] = f2bf(acc[i][j][0]); o[1] = f2bf(acc[i][j][1]);
          o[2] = f2bf(acc[i][j][2]); o[3] = f2bf(acc[i][j][3]);
          *reinterpret_cast<us4*>(vtb + ((size_t)((bb * 16 + h) * 128 + d) * 2048 + phys)) = o;
        }
      }
    } else {
#pragma unroll
      for (int i = 0; i < 4; ++i)
#pragma unroll
        for (int j = 0; j < 4; ++j) {
          const int gn = col0 + wn + j * 16 + l15;
#pragma unroll
          for (int r = 0; r < 4; ++r) {
            const int gm = row0 + wm + i * 16 + l4 * 4 + r;
            outq[(size_t)gm * 2048 + gn] = __float2bfloat16(acc[i][j][r]);
          }
        }
    }
  });
}

// RoPE in place on q and k, vectorized 8-wide (R16/R18-proven). q additionally pre-scaled
// by SC2 = (1/sqrt(128))*log2(e) so flash's softmax is P = exp2(sacc) with no multiply.
__global__ __launch_bounds__(256) void rope_k(__hip_bfloat16* __restrict__ q,
                                              __hip_bfloat16* __restrict__ k) {
  const int tid = blockIdx.x * 256 + threadIdx.x;
  const int i8 = tid & 7;
  const int h = (tid >> 3) & 15;
  const int row = (tid >> 7) & 4095;
  const int isk = tid >> 19;
  __hip_bfloat16* p = isk ? k : q;
  const float qs = isk ? 1.0f : 0.1275224187f;  // fold (1/sqrt(d))*log2e into q
  const int pos = row & 2047;
  const size_t base = (size_t)row * 2048 + h * 128 + i8 * 8;
  const short8 v1 = *reinterpret_cast<const short8*>(p + base);
  const short8 v2 = *reinterpret_cast<const short8*>(p + base + 64);
  short8 o1, o2;
#pragma unroll
  for (int j = 0; j < 8; ++j) {
    const int i = i8 * 8 + j;
    const float invf = exp2f((float)i * -0.20762050593046f);  // 10000^(-i/64)
    const float fr = (float)pos * invf;
    float sv, cv;
    sincosf(fr, &sv, &cv);
    const float x1 = bf2f(v1[j]), x2 = bf2f(v2[j]);
    o1[j] = (short)f2bf((x1 * cv - x2 * sv) * qs);
    o2[j] = (short)f2bf((x1 * sv + x2 * cv) * qs);
  }
  *reinterpret_cast<short8*>(p + base) = o1;
  *reinterpret_cast<short8*>(p + base + 64) = o2;
}

// Flash attention v10 (R16/R18-proven): K+VT LDS counted-vmcnt ring, 64KB, gll16 with
// pre-swizzled source, 8 loads/wave/tile -> vmcnt(8), never 0 in steady state.
// Q pre-roped+pre-scaled by rope_k -> P = exp2f(sacc); lr via ones-row MFMA.
// grid 512 (qt=bx>>5, bh=bx&31; bx%8=bh%8 pins each (b,h)'s 1MB KV set to one XCD L2).
// 4 waves x 32 q-rows (QBLK=128). Fixed-max softmax (scores bounded, fp32-safe).
// kv-permuted V^T (V-frag = one b128 ds_read); swapped QK^T / PV (S^T, O^T in-register).
__global__ __launch_bounds__(256) void flash_k(const __hip_bfloat16* __restrict__ q,
                                               const __hip_bfloat16* __restrict__ k,
                                               const __hip_bfloat16* __restrict__ vt,
                                               __hip_bfloat16* __restrict__ ao) {
  __shared__ char Ks[2][16384];   // K tile [64 kv][128 d], swizzled
  __shared__ char VTs[2][16384];  // V^T tile [128 d][64 kv permuted], swizzled
  const int tid = threadIdx.x, lane = tid & 63, wid = tid >> 6;
  const int bx = blockIdx.x;
  const int qt = bx >> 5, bh = bx & 31, b = bh >> 4, h = bh & 15;
  const int l15 = lane & 15, l4 = lane >> 4;

  short8 qf[2][4];
  const char* qB = (const char*)q;
#pragma unroll
  for (int mi = 0; mi < 2; ++mi)
#pragma unroll
    for (int kc = 0; kc < 4; ++kc) {
      const size_t off =
          ((size_t)(b * 2048 + qt * 128 + wid * 32 + mi * 16 + l15) * 2048 + h * 128 + kc * 32 + l4 * 8) * 2;
      qf[mi][kc] = *(const short8*)(qB + off);
    }

  f32x4 oacc[2][8] = {};
  f32x4 lracc[2] = {};  // ones-row MFMA accumulates sum(P) per q-col; rows identical

  const short8 ones = {(short)0x3F80, (short)0x3F80, (short)0x3F80, (short)0x3F80,
                       (short)0x3F80, (short)0x3F80, (short)0x3F80, (short)0x3F80};  // bf16 1.0

  const char* kbase = (const char*)k + ((size_t)(b * 2048) * 2048 + h * 128) * 2;
  const char* vtbase = (const char*)vt + ((size_t)bh * 128 * 2048) * 2;

  // gll16 staging geometry. K tile: 16 chunks of 1KB = 4 kv-rows x 256B;
  // krow=lane>>4, kcol=lane&15. VT tile: 16 chunks = 8 d-rows x 128B; vrow=lane>>3,
  // vcol=lane&7. LDS dest linear (lane*16), global source pre-swizzled ^(row&7).
  const int krow = lane >> 4, kcol = lane & 15;
  const int vrow = lane >> 3, vcol = lane & 7;

#define GSTAGE(T, S)                                                                          \
  {                                                                                           \
    const int kv0_ = (T)*64;                                                                  \
    _Pragma("unroll") for (int c_ = 0; c_ < 4; ++c_) {                                        \
      const int cid_ = wid * 4 + c_;                                                          \
      const int rk_ = cid_ * 4 + krow;                                                        \
      gll16(kbase + (size_t)(kv0_ + rk_) * 4096 + ((kcol ^ (rk_ & 7)) * 16),                  \
            Ks[S] + cid_ * 1024);                                                             \
      const int rv_ = cid_ * 8 + vrow;                                                        \
      gll16(vtbase + (size_t)rv_ * 4096 + (size_t)kv0_ * 2 + ((vcol ^ (rv_ & 7)) * 16),       \
            VTs[S] + cid_ * 1024);                                                            \
    }                                                                                         \
  }

  GSTAGE(0, 0);
  GSTAGE(1, 1);
  asm volatile("s_waitcnt vmcnt(8)" ::: "memory");  // tile 0's 8 loads landed
  __builtin_amdgcn_s_barrier();

  for (int t = 0; t < 32; ++t) {
    const int s = t & 1;

    // S^T = (Q K^T)^T : mfma(A=K rows, B=Q rows) -> C[kv][q], col=l15=q, row=l4*4+r=kv
    f32x4 sacc[2][4] = {};
#pragma unroll
    for (int kc = 0; kc < 4; ++kc) {
      short8 kf[4];
#pragma unroll
      for (int ni = 0; ni < 4; ++ni) {
        const int r = ni * 16 + l15;
        kf[ni] = *(const short8*)(Ks[s] + r * 256 + (((kc * 4 + l4) ^ (r & 7)) * 16));
      }
#pragma unroll
      for (int mi = 0; mi < 2; ++mi)
#pragma unroll
        for (int ni = 0; ni < 4; ++ni)
          sacc[mi][ni] = __builtin_amdgcn_mfma_f32_16x16x32_bf16(kf[ni], qf[mi][kc], sacc[mi][ni], 0, 0, 0);
    }

    // fixed-max softmax: Q carries SC2 -> P = exp2f(sacc) directly (|sacc| <= ~8.5,
    // P in [2^-10, ~360], fp32-safe). No row max, no mul, no row-sum VALU.
    unsigned int W[2][4][2];
#pragma unroll
    for (int mi = 0; mi < 2; ++mi)
#pragma unroll
      for (int ni = 0; ni < 4; ++ni) {
        W[mi][ni][0] = cvtpk(exp2f(sacc[mi][ni][0]), exp2f(sacc[mi][ni][1]));
        W[mi][ni][1] = cvtpk(exp2f(sacc[mi][ni][2]), exp2f(sacc[mi][ni][3]));
      }

    // O^T += (V^T) P ; lr += (ones) P  (matrix pipe computes the denominator)
#pragma unroll
    for (int kc = 0; kc < 2; ++kc) {
      union { u32x4 u; short8 s; } pfu[2];
#pragma unroll
      for (int mi = 0; mi < 2; ++mi) {
        pfu[mi].u[0] = W[mi][kc * 2][0];
        pfu[mi].u[1] = W[mi][kc * 2][1];
        pfu[mi].u[2] = W[mi][kc * 2 + 1][0];
        pfu[mi].u[3] = W[mi][kc * 2 + 1][1];
      }
#pragma unroll
      for (int nd = 0; nd < 8; ++nd) {
        const int r = nd * 16 + l15;
        const short8 vf = *(const short8*)(
            VTs[s] + r * 128 + (((kc * 4 + l4) ^ (r & 7)) * 16));
#pragma unroll
        for (int mi = 0; mi < 2; ++mi)
          oacc[mi][nd] = __builtin_amdgcn_mfma_f32_16x16x32_bf16(vf, pfu[mi].s, oacc[mi][nd], 0, 0, 0);
      }
#pragma unroll
      for (int mi = 0; mi < 2; ++mi)
        lracc[mi] = __builtin_amdgcn_mfma_f32_16x16x32_bf16(ones, pfu[mi].s, lracc[mi], 0, 0, 0);
    }

    asm volatile("s_waitcnt lgkmcnt(0)" ::: "memory");  // my reads of slot s retired
    __builtin_amdgcn_sched_barrier(0);
    __builtin_amdgcn_s_barrier();                       // bar1: ALL waves' reads retired
    if (t + 2 < 32) {
      GSTAGE(t + 2, s);                                 // overwrite freed slot
      asm volatile("s_waitcnt vmcnt(8)" ::: "memory");  // tile t+1 (8 oldest) landed
    } else if (t + 2 == 32) {
      asm volatile("s_waitcnt vmcnt(0)" ::: "memory");  // epilogue drain: tile 31
    }
    __builtin_amdgcn_s_barrier();                       // bar2: slot s^1 published
  }

  // epilogue: O^T layout -> lane holds q = mi*16+l15, d = nd*16 + l4*4 + r (4 consecutive)
#pragma unroll
  for (int mi = 0; mi < 2; ++mi) {
    const float inv = 1.f / lracc[mi][0];
    const int qrow = qt * 128 + wid * 32 + mi * 16 + l15;
    const size_t rowoff = ((size_t)(b * 2048 + qrow)) * 2048 + h * 128;
#pragma unroll
    for (int nd = 0; nd < 8; ++nd) {
      us4 o;
      o[0] = f2bf(oacc[mi][nd][0] * inv);
      o[1] = f2bf(oacc[mi][nd][1] * inv);
      o[2] = f2bf(oacc[mi][nd][2] * inv);
      o[3] = f2bf(oacc[mi][nd][3] * inv);
      *reinterpret_cast<us4*>(ao + rowoff + nd * 16 + l4 * 4) = o;
    }
  }
#undef GSTAGE
}

extern "C" void kernel_launch(void* const* d_in, const int* in_sizes, int n_in,
                              void* d_out, int out_size, void* d_ws, size_t ws_size,
                              hipStream_t stream) {
  const float* x  = (const float*)d_in[0];
  const float* Wq = (const float*)d_in[1];
  const float* Wk = (const float*)d_in[2];
  const float* Wv = (const float*)d_in[3];
  const float* Wo = (const float*)d_in[4];
  float* out = (float*)d_out;

  const size_t MK = (size_t)4096 * 2048;  // 8,388,608
  const size_t WN = (size_t)2048 * 2048;  // 4,194,304
  if (ws_size < (4 * MK + WN) * 2) return;  // need ~72MB

  __hip_bfloat16* ws  = (__hip_bfloat16*)d_ws;
  __hip_bfloat16* xb  = ws;             // also reused as attention output (aob)
  __hip_bfloat16* qb  = ws + MK;
  __hip_bfloat16* kb  = ws + 2 * MK;
  __hip_bfloat16* vtb = ws + 3 * MK;
  __hip_bfloat16* wsl = ws + 4 * MK;    // holds Wo bf16 for the final GEMM
  __hip_bfloat16* aob = xb;
  // d_out as scratch for Wq/Wk/Wv bf16 (dead before final GEMM overwrites d_out)
  __hip_bfloat16* dq = (__hip_bfloat16*)d_out;
  __hip_bfloat16* dk = dq + WN;
  __hip_bfloat16* dv = dk + WN;

  const int nx4 = (int)(MK / 4), nw4 = (int)(WN / 4);
  cast5<<<dim3((nx4 + 4 * nw4) / 256), 256, 0, stream>>>(x, Wq, Wk, Wv, Wo,
                                                         xb, dq, dk, dv, wsl, nx4, nw4);
  gemm_qkv<<<dim3(32, 48), 256, 0, stream>>>(xb, dq, dk, dv, qb, kb, vtb);
  rope_k<<<4096, 256, 0, stream>>>(qb, kb);
  flash_k<<<512, 256, 0, stream>>>(qb, kb, vtb, aob);
  gemm_bt<1><<<dim3(32, 16), 256, 0, stream>>>(aob, wsl, out, 4096, 2048, 2048);
}

// Round 22
// 254.399 us; speedup vs baseline: 1.2120x; 1.0005x over previous
//
#include <hip/hip_runtime.h>
#include <hip/hip_bf16.h>

// BaseTimeAttention: out = ((softmax(rope(xWq)·rope(xWk)^T/sqrt(d)))·(xWv)) @ Wo^T
// bf16 MFMA everywhere (no fp32 MFMA on CDNA4), fp32 accum + fp32 softmax (exp2 domain).
// d_ws layout (bf16 elems): xb/aob(8.4M) | qb(8.4M) | kb(8.4M) | vtb(8.4M) | wsl(4.2M) = 72MB
// d_out doubles as scratch for Wq/Wk/Wv bf16 (25.2MB < 33.5MB; dead before the final GEMM
// overwrites d_out); Wo bf16 lives in wsl from the start (nothing else touches wsl).
// R22 = R21 (proven best 254.5us) + grid-stride cast5 (G11), nothing else changed.

typedef __attribute__((ext_vector_type(8))) short short8;
typedef __attribute__((ext_vector_type(4))) float f32x4;
typedef __attribute__((ext_vector_type(4))) unsigned short us4;
typedef __attribute__((ext_vector_type(4))) unsigned int u32x4;

__device__ __forceinline__ void gll16(const void* g, void* l) {
  __builtin_amdgcn_global_load_lds((const __attribute__((address_space(1))) void*)g,
                                   (__attribute__((address_space(3))) void*)l, 16, 0, 0);
}

__device__ __forceinline__ unsigned short f2bf(float f) {
  __hip_bfloat16 h = __float2bfloat16(f);
  return *reinterpret_cast<unsigned short*>(&h);
}

__device__ __forceinline__ float bf2f(short s) {
  union { unsigned int u; float f; } c;
  c.u = ((unsigned int)(unsigned short)s) << 16;
  return c.f;
}

// pack two f32 -> one u32 of 2 bf16 (lo,hi) via HW instruction
__device__ __forceinline__ unsigned int cvtpk(float lo, float hi) {
  unsigned int r;
  asm("v_cvt_pk_bf16_f32 %0, %1, %2" : "=v"(r) : "v"(lo), "v"(hi));
  return r;
}

// T1 XCD-aware block remap (bijective; requires gridDim.y % 8 == 0).
__device__ __forceinline__ void xcd_remap(int& Bx, int& By) {
  const int flat = blockIdx.y * gridDim.x + blockIdx.x;
  const int xcd = flat & 7, idx = flat >> 3;
  const int ppx = gridDim.y >> 3;  // W-panels per XCD
  By = xcd * ppx + (idx % ppx);
  Bx = idx / ppx;
}

// one launch: cast x + Wq + Wk + Wv + Wo (f32 -> bf16, float4-wide), grid-stride (G11)
__global__ __launch_bounds__(256) void cast5(const float* __restrict__ x,
                                             const float* __restrict__ wq,
                                             const float* __restrict__ wk,
                                             const float* __restrict__ wv,
                                             const float* __restrict__ wo,
                                             __hip_bfloat16* __restrict__ xb,
                                             __hip_bfloat16* __restrict__ dq,
                                             __hip_bfloat16* __restrict__ dk,
                                             __hip_bfloat16* __restrict__ dv,
                                             __hip_bfloat16* __restrict__ dwo,
                                             int nx4, int nw4) {
  const int ntot = nx4 + 4 * nw4;
  const int stride = gridDim.x * 256;
  for (int i = blockIdx.x * 256 + threadIdx.x; i < ntot; i += stride) {
    const float* in;
    __hip_bfloat16* out;
    int j = i;
    if (i < nx4) { in = x; out = xb; }
    else if ((j = i - nx4) < nw4) { in = wq; out = dq; }
    else if ((j -= nw4) < nw4) { in = wk; out = dk; }
    else if ((j -= nw4) < nw4) { in = wv; out = dv; }
    else { j -= nw4; in = wo; out = dwo; }
    const float4 v = reinterpret_cast<const float4*>(in)[j];
    us4 o;
    o[0] = f2bf(v.x); o[1] = f2bf(v.y); o[2] = f2bf(v.z); o[3] = f2bf(v.w);
    *reinterpret_cast<us4*>(out + (size_t)j * 4) = o;
  }
}

// ---- shared GEMM core v2 (proven R12/R14/R16/R18/R21): counted-vmcnt double-buffered
// ring (T4). C = A(MxK) * Bt(NxK)^T, 128x128 tile, BK=64, 4 waves (2x2 of 64x64).
// LDS tiles [128 rows][64 cols bf16], XOR-swizzled: phys 16B-chunk = logical ^ (row&7).
template <typename EPI>
__device__ __forceinline__ void gemm_core(const __hip_bfloat16* A, const __hip_bfloat16* Bt,
                                          int row0, int col0, int K, EPI epi) {
  __shared__ char As[2][16384];
  __shared__ char Bs[2][16384];
  const int tid = threadIdx.x;
  const int lane = tid & 63, wid = tid >> 6;
  const int l15 = lane & 15, l4 = lane >> 4;
  const int wm = (wid >> 1) * 64, wn = (wid & 1) * 64;

  f32x4 acc[4][4] = {};

  const int rs = lane >> 3;       // row within 1KB staging chunk (8 rows x 128B)
  const int cs = lane & 7;        // 16B chunk within row
  const int cg = cs ^ rs;         // pre-swizzled global source chunk
  const char* Ab = (const char*)A;
  const char* Bb = (const char*)Bt;
  const size_t Kb = (size_t)K * 2;
  const int NT = K >> 6;          // K-tiles of 64

#define GSTAGE(T, S)                                                                      \
  {                                                                                       \
    const int k0_ = (T) << 6;                                                             \
    _Pragma("unroll") for (int c_ = 0; c_ < 4; ++c_) {                                    \
      const int cid_ = wid * 4 + c_;                                                      \
      const int r_ = cid_ * 8 + rs;                                                       \
      gll16(Ab + (size_t)(row0 + r_) * Kb + (size_t)k0_ * 2 + cg * 16, As[S] + cid_ * 1024); \
      gll16(Bb + (size_t)(col0 + r_) * Kb + (size_t)k0_ * 2 + cg * 16, Bs[S] + cid_ * 1024); \
    }                                                                                     \
  }

  GSTAGE(0, 0);
  GSTAGE(1, 1);
  asm volatile("s_waitcnt vmcnt(8)" ::: "memory");  // tile 0's 8 loads landed
  __builtin_amdgcn_s_barrier();

  for (int t = 0; t < NT; ++t) {
    const int s = t & 1;
    short8 a[2][4], b[2][4];
#pragma unroll
    for (int kc = 0; kc < 2; ++kc)
#pragma unroll
      for (int i = 0; i < 4; ++i) {
        const int ra = wm + i * 16 + l15;
        a[kc][i] = *(const short8*)(As[s] + ra * 128 + (((kc * 4 + l4) ^ (ra & 7)) * 16));
        const int rb = wn + i * 16 + l15;
        b[kc][i] = *(const short8*)(Bs[s] + rb * 128 + (((kc * 4 + l4) ^ (rb & 7)) * 16));
      }
    asm volatile("s_waitcnt lgkmcnt(0)" ::: "memory");  // my reads of slot s retired
    __builtin_amdgcn_sched_barrier(0);
    __builtin_amdgcn_s_barrier();                       // bar1: ALL waves' reads retired
    if (t + 2 < NT) {
      GSTAGE(t + 2, s);                                 // overwrite freed slot
      asm volatile("s_waitcnt vmcnt(8)" ::: "memory");  // tile t+1 (8 oldest) landed
    } else if (t + 2 == NT) {
      asm volatile("s_waitcnt vmcnt(0)" ::: "memory");  // epilogue drain: tile NT-1
    }
    __builtin_amdgcn_s_barrier();                       // bar2: slot s^1 published
#pragma unroll
    for (int kc = 0; kc < 2; ++kc) {
      __builtin_amdgcn_s_setprio(1);
#pragma unroll
      for (int i = 0; i < 4; ++i)
#pragma unroll
        for (int j = 0; j < 4; ++j)
          acc[i][j] = __builtin_amdgcn_mfma_f32_16x16x32_bf16(a[kc][i], b[kc][j], acc[i][j], 0, 0, 0);
      __builtin_amdgcn_s_setprio(0);
    }
  }
  epi(acc, wm, wn, l15, l4);
#undef GSTAGE
}

// MODE 0: bf16 row-major. MODE 1: f32 row-major.
// MODE 2: V^T per (b,h), kv-PERMUTED: phys = (kv&~31)+((kv>>2)&3)*8+((kv>>4)&1)*4+(kv&3).
template <int MODE>
__global__ __launch_bounds__(256) void gemm_bt(const __hip_bfloat16* __restrict__ A,
                                               const __hip_bfloat16* __restrict__ Bt,
                                               void* __restrict__ Cout,
                                               int M, int N, int K) {
  int Bx, By;
  xcd_remap(Bx, By);  // T1: same-XCD blocks share W-panels + consecutive same A-tile
  const int row0 = Bx * 128, col0 = By * 128;
  gemm_core(A, Bt, row0, col0, K, [=](f32x4 (&acc)[4][4], int wm, int wn, int l15, int l4) {
    if (MODE == 2) {
      __hip_bfloat16* vt = (__hip_bfloat16*)Cout;
#pragma unroll
      for (int i = 0; i < 4; ++i) {
        const int gm = row0 + wm + i * 16 + l4 * 4;
        const int bb = gm >> 11, kvb = gm & 2047;
        const int phys = (kvb & ~31) + (((kvb >> 2) & 3) << 3) + (((kvb >> 4) & 1) << 2);
#pragma unroll
        for (int j = 0; j < 4; ++j) {
          const int gn = col0 + wn + j * 16 + l15;
          const int h = gn >> 7, d = gn & 127;
          us4 o;
          o[0] = f2bf(acc[i][j][0]); o[1] = f2bf(acc[i][j][1]);
          o[2] = f2bf(acc[i][j][2]); o[3] = f2bf(acc[i][j][3]);
          *reinterpret_cast<us4*>(vt + ((size_t)((bb * 16 + h) * 128 + d) * 2048 + phys)) = o;
        }
      }
    } else {
#pragma unroll
      for (int i = 0; i < 4; ++i)
#pragma unroll
        for (int j = 0; j < 4; ++j) {
          const int gn = col0 + wn + j * 16 + l15;
#pragma unroll
          for (int r = 0; r < 4; ++r) {
            const int gm = row0 + wm + i * 16 + l4 * 4 + r;
            if (MODE == 0)
              ((__hip_bfloat16*)Cout)[(size_t)gm * N + gn] = __float2bfloat16(acc[i][j][r]);
            else
              ((float*)Cout)[(size_t)gm * N + gn] = acc[i][j][r];
          }
        }
    }
  });
}

// fused QKV GEMM: grid (32, 48). By 0-15 -> Wq->qb (row-major bf16); 16-31 -> Wk->kb;
// 32-47 -> Wv->vtb (kv-permuted V^T layout). A = xb for all. T1 XCD remap.
__global__ __launch_bounds__(256) void gemm_qkv(const __hip_bfloat16* __restrict__ A,
                                                const __hip_bfloat16* __restrict__ Wq,
                                                const __hip_bfloat16* __restrict__ Wk,
                                                const __hip_bfloat16* __restrict__ Wv,
                                                __hip_bfloat16* __restrict__ qb,
                                                __hip_bfloat16* __restrict__ kb,
                                                __hip_bfloat16* __restrict__ vtb) {
  int Bx, By;
  xcd_remap(Bx, By);
  const int row0 = Bx * 128;
  const int sel = By >> 4;                 // 0=q, 1=k, 2=v
  const int col0 = (By & 15) * 128;
  const __hip_bfloat16* Bt = (sel == 0) ? Wq : (sel == 1) ? Wk : Wv;
  __hip_bfloat16* outq = (sel == 0) ? qb : kb;

  gemm_core(A, Bt, row0, col0, 2048, [=](f32x4 (&acc)[4][4], int wm, int wn, int l15, int l4) {
    if (sel == 2) {
#pragma unroll
      for (int i = 0; i < 4; ++i) {
        const int gm = row0 + wm + i * 16 + l4 * 4;
        const int bb = gm >> 11, kvb = gm & 2047;
        const int phys = (kvb & ~31) + (((kvb >> 2) & 3) << 3) + (((kvb >> 4) & 1) << 2);
#pragma unroll
        for (int j = 0; j < 4; ++j) {
          const int gn = col0 + wn + j * 16 + l15;
          const int h = gn >> 7, d = gn & 127;
          us4 o;
          o[0] = f2bf(acc[i][j][0]); o[1] = f2bf(acc[i][j][1]);
          o[2] = f2bf(acc[i][j][2]); o[3] = f2bf(acc[i][j][3]);
          *reinterpret_cast<us4*>(vtb + ((size_t)((bb * 16 + h) * 128 + d) * 2048 + phys)) = o;
        }
      }
    } else {
#pragma unroll
      for (int i = 0; i < 4; ++i)
#pragma unroll
        for (int j = 0; j < 4; ++j) {
          const int gn = col0 + wn + j * 16 + l15;
#pragma unroll
          for (int r = 0; r < 4; ++r) {
            const int gm = row0 + wm + i * 16 + l4 * 4 + r;
            outq[(size_t)gm * 2048 + gn] = __float2bfloat16(acc[i][j][r]);
          }
        }
    }
  });
}

// RoPE in place on q and k, vectorized 8-wide (R16/R18/R21-proven). q additionally
// pre-scaled by SC2 = (1/sqrt(128))*log2(e) so flash's softmax is P = exp2(sacc).
__global__ __launch_bounds__(256) void rope_k(__hip_bfloat16* __restrict__ q,
                                              __hip_bfloat16* __restrict__ k) {
  const int tid = blockIdx.x * 256 + threadIdx.x;
  const int i8 = tid & 7;
  const int h = (tid >> 3) & 15;
  const int row = (tid >> 7) & 4095;
  const int isk = tid >> 19;
  __hip_bfloat16* p = isk ? k : q;
  const float qs = isk ? 1.0f : 0.1275224187f;  // fold (1/sqrt(d))*log2e into q
  const int pos = row & 2047;
  const size_t base = (size_t)row * 2048 + h * 128 + i8 * 8;
  const short8 v1 = *reinterpret_cast<const short8*>(p + base);
  const short8 v2 = *reinterpret_cast<const short8*>(p + base + 64);
  short8 o1, o2;
#pragma unroll
  for (int j = 0; j < 8; ++j) {
    const int i = i8 * 8 + j;
    const float invf = exp2f((float)i * -0.20762050593046f);  // 10000^(-i/64)
    const float fr = (float)pos * invf;
    float sv, cv;
    sincosf(fr, &sv, &cv);
    const float x1 = bf2f(v1[j]), x2 = bf2f(v2[j]);
    o1[j] = (short)f2bf((x1 * cv - x2 * sv) * qs);
    o2[j] = (short)f2bf((x1 * sv + x2 * cv) * qs);
  }
  *reinterpret_cast<short8*>(p + base) = o1;
  *reinterpret_cast<short8*>(p + base + 64) = o2;
}

// Flash attention v10 (R16/R18/R21-proven): K+VT LDS counted-vmcnt ring, 64KB, gll16
// with pre-swizzled source, 8 loads/wave/tile -> vmcnt(8), never 0 in steady state.
// Q pre-roped+pre-scaled by rope_k -> P = exp2f(sacc); lr via ones-row MFMA.
// grid 512 (qt=bx>>5, bh=bx&31; bx%8=bh%8 pins each (b,h)'s 1MB KV set to one XCD L2).
// 4 waves x 32 q-rows (QBLK=128). Fixed-max softmax (scores bounded, fp32-safe).
// kv-permuted V^T (V-frag = one b128 ds_read); swapped QK^T / PV (S^T, O^T in-register).
__global__ __launch_bounds__(256) void flash_k(const __hip_bfloat16* __restrict__ q,
                                               const __hip_bfloat16* __restrict__ k,
                                               const __hip_bfloat16* __restrict__ vt,
                                               __hip_bfloat16* __restrict__ ao) {
  __shared__ char Ks[2][16384];   // K tile [64 kv][128 d], swizzled
  __shared__ char VTs[2][16384];  // V^T tile [128 d][64 kv permuted], swizzled
  const int tid = threadIdx.x, lane = tid & 63, wid = tid >> 6;
  const int bx = blockIdx.x;
  const int qt = bx >> 5, bh = bx & 31, b = bh >> 4, h = bh & 15;
  const int l15 = lane & 15, l4 = lane >> 4;

  short8 qf[2][4];
  const char* qB = (const char*)q;
#pragma unroll
  for (int mi = 0; mi < 2; ++mi)
#pragma unroll
    for (int kc = 0; kc < 4; ++kc) {
      const size_t off =
          ((size_t)(b * 2048 + qt * 128 + wid * 32 + mi * 16 + l15) * 2048 + h * 128 + kc * 32 + l4 * 8) * 2;
      qf[mi][kc] = *(const short8*)(qB + off);
    }

  f32x4 oacc[2][8] = {};
  f32x4 lracc[2] = {};  // ones-row MFMA accumulates sum(P) per q-col; rows identical

  const short8 ones = {(short)0x3F80, (short)0x3F80, (short)0x3F80, (short)0x3F80,
                       (short)0x3F80, (short)0x3F80, (short)0x3F80, (short)0x3F80};  // bf16 1.0

  const char* kbase = (const char*)k + ((size_t)(b * 2048) * 2048 + h * 128) * 2;
  const char* vtbase = (const char*)vt + ((size_t)bh * 128 * 2048) * 2;

  // gll16 staging geometry. K tile: 16 chunks of 1KB = 4 kv-rows x 256B;
  // krow=lane>>4, kcol=lane&15. VT tile: 16 chunks = 8 d-rows x 128B; vrow=lane>>3,
  // vcol=lane&7. LDS dest linear (lane*16), global source pre-swizzled ^(row&7).
  const int krow = lane >> 4, kcol = lane & 15;
  const int vrow = lane >> 3, vcol = lane & 7;

#define GSTAGE(T, S)                                                                          \
  {                                                                                           \
    const int kv0_ = (T)*64;                                                                  \
    _Pragma("unroll") for (int c_ = 0; c_ < 4; ++c_) {                                        \
      const int cid_ = wid * 4 + c_;                                                          \
      const int rk_ = cid_ * 4 + krow;                                                        \
      gll16(kbase + (size_t)(kv0_ + rk_) * 4096 + ((kcol ^ (rk_ & 7)) * 16),                  \
            Ks[S] + cid_ * 1024);                                                             \
      const int rv_ = cid_ * 8 + vrow;                                                        \
      gll16(vtbase + (size_t)rv_ * 4096 + (size_t)kv0_ * 2 + ((vcol ^ (rv_ & 7)) * 16),       \
            VTs[S] + cid_ * 1024);                                                            \
    }                                                                                         \
  }

  GSTAGE(0, 0);
  GSTAGE(1, 1);
  asm volatile("s_waitcnt vmcnt(8)" ::: "memory");  // tile 0's 8 loads landed
  __builtin_amdgcn_s_barrier();

  for (int t = 0; t < 32; ++t) {
    const int s = t & 1;

    // S^T = (Q K^T)^T : mfma(A=K rows, B=Q rows) -> C[kv][q], col=l15=q, row=l4*4+r=kv
    f32x4 sacc[2][4] = {};
#pragma unroll
    for (int kc = 0; kc < 4; ++kc) {
      short8 kf[4];
#pragma unroll
      for (int ni = 0; ni < 4; ++ni) {
        const int r = ni * 16 + l15;
        kf[ni] = *(const short8*)(Ks[s] + r * 256 + (((kc * 4 + l4) ^ (r & 7)) * 16));
      }
#pragma unroll
      for (int mi = 0; mi < 2; ++mi)
#pragma unroll
        for (int ni = 0; ni < 4; ++ni)
          sacc[mi][ni] = __builtin_amdgcn_mfma_f32_16x16x32_bf16(kf[ni], qf[mi][kc], sacc[mi][ni], 0, 0, 0);
    }

    // fixed-max softmax: Q carries SC2 -> P = exp2f(sacc) directly (|sacc| <= ~8.5,
    // P in [2^-10, ~360], fp32-safe). No row max, no mul, no row-sum VALU.
    unsigned int W[2][4][2];
#pragma unroll
    for (int mi = 0; mi < 2; ++mi)
#pragma unroll
      for (int ni = 0; ni < 4; ++ni) {
        W[mi][ni][0] = cvtpk(exp2f(sacc[mi][ni][0]), exp2f(sacc[mi][ni][1]));
        W[mi][ni][1] = cvtpk(exp2f(sacc[mi][ni][2]), exp2f(sacc[mi][ni][3]));
      }

    // O^T += (V^T) P ; lr += (ones) P  (matrix pipe computes the denominator)
#pragma unroll
    for (int kc = 0; kc < 2; ++kc) {
      union { u32x4 u; short8 s; } pfu[2];
#pragma unroll
      for (int mi = 0; mi < 2; ++mi) {
        pfu[mi].u[0] = W[mi][kc * 2][0];
        pfu[mi].u[1] = W[mi][kc * 2][1];
        pfu[mi].u[2] = W[mi][kc * 2 + 1][0];
        pfu[mi].u[3] = W[mi][kc * 2 + 1][1];
      }
#pragma unroll
      for (int nd = 0; nd < 8; ++nd) {
        const int r = nd * 16 + l15;
        const short8 vf = *(const short8*)(
            VTs[s] + r * 128 + (((kc * 4 + l4) ^ (r & 7)) * 16));
#pragma unroll
        for (int mi = 0; mi < 2; ++mi)
          oacc[mi][nd] = __builtin_amdgcn_mfma_f32_16x16x32_bf16(vf, pfu[mi].s, oacc[mi][nd], 0, 0, 0);
      }
#pragma unroll
      for (int mi = 0; mi < 2; ++mi)
        lracc[mi] = __builtin_amdgcn_mfma_f32_16x16x32_bf16(ones, pfu[mi].s, lracc[mi], 0, 0, 0);
    }

    asm volatile("s_waitcnt lgkmcnt(0)" ::: "memory");  // my reads of slot s retired
    __builtin_amdgcn_sched_barrier(0);
    __builtin_amdgcn_s_barrier();                       // bar1: ALL waves' reads retired
    if (t + 2 < 32) {
      GSTAGE(t + 2, s);                                 // overwrite freed slot
      asm volatile("s_waitcnt vmcnt(8)" ::: "memory");  // tile t+1 (8 oldest) landed
    } else if (t + 2 == 32) {
      asm volatile("s_waitcnt vmcnt(0)" ::: "memory");  // epilogue drain: tile 31
    }
    __builtin_amdgcn_s_barrier();                       // bar2: slot s^1 published
  }

  // epilogue: O^T layout -> lane holds q = mi*16+l15, d = nd*16 + l4*4 + r (4 consecutive)
#pragma unroll
  for (int mi = 0; mi < 2; ++mi) {
    const float inv = 1.f / lracc[mi][0];
    const int qrow = qt * 128 + wid * 32 + mi * 16 + l15;
    const size_t rowoff = ((size_t)(b * 2048 + qrow)) * 2048 + h * 128;
#pragma unroll
    for (int nd = 0; nd < 8; ++nd) {
      us4 o;
      o[0] = f2bf(oacc[mi][nd][0] * inv);
      o[1] = f2bf(oacc[mi][nd][1] * inv);
      o[2] = f2bf(oacc[mi][nd][2] * inv);
      o[3] = f2bf(oacc[mi][nd][3] * inv);
      *reinterpret_cast<us4*>(ao + rowoff + nd * 16 + l4 * 4) = o;
    }
  }
#undef GSTAGE
}

extern "C" void kernel_launch(void* const* d_in, const int* in_sizes, int n_in,
                              void* d_out, int out_size, void* d_ws, size_t ws_size,
                              hipStream_t stream) {
  const float* x  = (const float*)d_in[0];
  const float* Wq = (const float*)d_in[1];
  const float* Wk = (const float*)d_in[2];
  const float* Wv = (const float*)d_in[3];
  const float* Wo = (const float*)d_in[4];
  float* out = (float*)d_out;

  const size_t MK = (size_t)4096 * 2048;  // 8,388,608
  const size_t WN = (size_t)2048 * 2048;  // 4,194,304
  if (ws_size < (4 * MK + WN) * 2) return;  // need ~72MB

  __hip_bfloat16* ws  = (__hip_bfloat16*)d_ws;
  __hip_bfloat16* xb  = ws;             // also reused as attention output (aob)
  __hip_bfloat16* qb  = ws + MK;
  __hip_bfloat16* kb  = ws + 2 * MK;
  __hip_bfloat16* vtb = ws + 3 * MK;
  __hip_bfloat16* wsl = ws + 4 * MK;    // holds Wo bf16 for the final GEMM
  __hip_bfloat16* aob = xb;
  // d_out as scratch for Wq/Wk/Wv bf16 (dead before final GEMM overwrites d_out)
  __hip_bfloat16* dq = (__hip_bfloat16*)d_out;
  __hip_bfloat16* dk = dq + WN;
  __hip_bfloat16* dv = dk + WN;

  const int nx4 = (int)(MK / 4), nw4 = (int)(WN / 4);
  cast5<<<2048, 256, 0, stream>>>(x, Wq, Wk, Wv, Wo, xb, dq, dk, dv, wsl, nx4, nw4);
  gemm_qkv<<<dim3(32, 48), 256, 0, stream>>>(xb, dq, dk, dv, qb, kb, vtb);
  rope_k<<<4096, 256, 0, stream>>>(qb, kb);
  flash_k<<<512, 256, 0, stream>>>(qb, kb, vtb, aob);
  gemm_bt<1><<<dim3(32, 16), 256, 0, stream>>>(aob, wsl, out, 4096, 2048, 2048);
}